// Round 11
// baseline (121.714 us; speedup 1.0000x reference)
//
#include <hip/hip_runtime.h>
#include <math.h>

namespace {
constexpr int kB = 4;
constexpr int kS = 4096;
constexpr int kH = 4096;
constexpr int kE = 16;
constexpr int kTokens = kB * kS;            // 16384
constexpr int kT = 4;                       // tokens per wave (ALL 16 experts)
constexpr int kWaves = 4;
constexpr int kThreads = 64 * kWaves;       // 256
constexpr int kTokBlk = kT * kWaves;        // 16 tokens per block
constexpr int kGrid = kTokens / kTokBlk;    // 1024 = 4 blocks/CU, all resident
constexpr int kChunk = 256;                 // floats of H per j-iter (float4/lane)
constexpr int kNC = kH / kChunk;            // 16
}  // namespace

// Pure-streaming gate GEMM. CRITICAL: no runtime indexing of any register
// array anywhere (rule #20) — previous rounds' `acc[lane][e]` epilogue read
// demoted the whole accumulator to scratch (112 MB of spill traffic, VGPR=64).
// All acc/xv/wv/p accesses below are compile-time indices.
__global__ __launch_bounds__(kThreads) void router_main(
    const float* __restrict__ x, const float* __restrict__ W,
    float* __restrict__ out_probs,   // [kTokens][2]
    float* __restrict__ out_idx,     // [kTokens][2] (indices as float)
    float* __restrict__ gpart) {     // [kGrid][32]: cnt[16], psum[16] per block
  __shared__ float s_cnt[kE];
  __shared__ float s_psum[kE];

  const int tid = threadIdx.x;
  const int wave = tid >> 6;
  const int lane = tid & 63;
  const int tok0 = blockIdx.x * kTokBlk + wave * kT;

  if (tid < kE) { s_cnt[tid] = 0.f; s_psum[tid] = 0.f; }

  const float* xb = x + (size_t)tok0 * kH + lane * 4;
  const float* wb = W + lane * 4;

  float acc[kT][kE];
#pragma unroll
  for (int t = 0; t < kT; ++t)
#pragma unroll
    for (int e = 0; e < kE; ++e) acc[t][e] = 0.f;

#pragma unroll 1
  for (int j = 0; j < kNC; ++j) {
    const size_t off = (size_t)j * kChunk;
    // x: 4 coalesced float4 (the HBM stream), issued up front.
    float4 xv[kT];
#pragma unroll
    for (int t = 0; t < kT; ++t)
      xv[t] = *reinterpret_cast<const float4*>(xb + (size_t)t * kH + off);
    // W: 4 sub-phases x 4 rows (wv reused -> only 16 live regs for W).
#pragma unroll
    for (int p = 0; p < 4; ++p) {
      float4 wv[4];
#pragma unroll
      for (int e = 0; e < 4; ++e)
        wv[e] = *reinterpret_cast<const float4*>(
            wb + (size_t)(p * 4 + e) * kH + off);
#pragma unroll
      for (int e = 0; e < 4; ++e) {
        const int ei = p * 4 + e;
#pragma unroll
        for (int t = 0; t < kT; ++t) {
          acc[t][ei] = fmaf(xv[t].x, wv[e].x, acc[t][ei]);
          acc[t][ei] = fmaf(xv[t].y, wv[e].y, acc[t][ei]);
          acc[t][ei] = fmaf(xv[t].z, wv[e].z, acc[t][ei]);
          acc[t][ei] = fmaf(xv[t].w, wv[e].w, acc[t][ei]);
        }
      }
    }
  }

  // Butterfly: every lane ends with full-H sums for the wave's 4x16 tile.
#pragma unroll
  for (int off = 1; off < 64; off <<= 1) {
#pragma unroll
    for (int t = 0; t < kT; ++t)
#pragma unroll
      for (int e = 0; e < kE; ++e)
        acc[t][e] += __shfl_xor(acc[t][e], off, 64);
  }

  // Static-index extraction of this lane's token (NO acc[lane][...]!).
  float l[kE];
#pragma unroll
  for (int t = 0; t < kT; ++t) {
    if (lane == t) {
#pragma unroll
      for (int e = 0; e < kE; ++e) l[e] = acc[t][e];
    }
  }

  __syncthreads();   // s_cnt/s_psum zeroed before any atomics land

  // Lanes 0..3: one token each — softmax, top-2, outputs, aux partials.
  if (lane < kT) {
    const int tok = tok0 + lane;

    float m = l[0];
#pragma unroll
    for (int e = 1; e < kE; ++e) m = fmaxf(m, l[e]);
    float p[kE];
    float s = 0.f;
#pragma unroll
    for (int e = 0; e < kE; ++e) { p[e] = __expf(l[e] - m); s += p[e]; }
    const float inv = 1.f / s;
#pragma unroll
    for (int e = 0; e < kE; ++e) p[e] *= inv;

    // top-2 on probs (reference: top_k AFTER softmax; ties -> lowest index).
    // Strict > scans with static indices only (p[i2] would demote p[]).
    int i1 = 0;
    float v1 = p[0];
#pragma unroll
    for (int e = 1; e < kE; ++e)
      if (p[e] > v1) { v1 = p[e]; i1 = e; }
    int i2 = -1;
    float v2 = -1.f;   // probs >= 0, so first non-i1 max wins (lowest index)
#pragma unroll
    for (int e = 0; e < kE; ++e) {
      if (e == i1) continue;
      if (p[e] > v2) { v2 = p[e]; i2 = e; }
    }

    const float ns = 1.f / (v1 + v2);
    out_probs[tok * 2 + 0] = v1 * ns;
    out_probs[tok * 2 + 1] = v2 * ns;
    out_idx[tok * 2 + 0] = (float)i1;
    out_idx[tok * 2 + 1] = (float)i2;

#pragma unroll
    for (int e = 0; e < kE; ++e) atomicAdd(&s_psum[e], p[e]);
    atomicAdd(&s_cnt[i1], 1.f);
    atomicAdd(&s_cnt[i2], 1.f);
  }
  __syncthreads();
  // Per-block partials (coalesced store); reduced by aux_finish.
  if (tid < 2 * kE)
    gpart[(size_t)blockIdx.x * 2 * kE + tid] =
        (tid < kE) ? s_cnt[tid] : s_psum[tid - kE];
}

// Reduce per-block partials; aux = E * sum_e (cnt_e/B) * (psum_e/(B*S)).
__global__ __launch_bounds__(1024) void aux_finish(
    const float* __restrict__ gpart, float* __restrict__ out_aux) {
  __shared__ float s_red[32][32];
  __shared__ float s_final[32];
  const int tid = threadIdx.x;
  const int c = tid & 31;       // column: 0-15 cnt, 16-31 psum
  const int r0 = tid >> 5;      // row-slice 0..31
  float s = 0.f;
  for (int k = 0; k < kGrid / 32; ++k)
    s += gpart[(size_t)(r0 * (kGrid / 32) + k) * 32 + c];
  s_red[r0][c] = s;
  __syncthreads();
  if (tid < 32) {
    float t = 0.f;
    for (int r = 0; r < 32; ++r) t += s_red[r][tid];
    s_final[tid] = t;
  }
  __syncthreads();
  if (tid == 0) {
    double acc = 0.0;
    for (int e = 0; e < kE; ++e)
      acc += (double)s_final[e] * (double)s_final[kE + e];
    out_aux[0] = (float)(acc * (double)kE / ((double)kB * (double)kB * (double)kS));
  }
}

extern "C" void kernel_launch(void* const* d_in, const int* in_sizes, int n_in,
                              void* d_out, int out_size, void* d_ws, size_t ws_size,
                              hipStream_t stream) {
  const float* x = (const float*)d_in[0];   // [B,S,H] f32
  const float* W = (const float*)d_in[1];   // [E,H]   f32
  float* out = (float*)d_out;               // [32768 probs][32768 idx][1 aux]
  float* gpart = (float*)d_ws;              // [kGrid][32], fully overwritten

  router_main<<<kGrid, kThreads, 0, stream>>>(
      x, W, out, out + 2 * kTokens, gpart);
  aux_finish<<<1, 1024, 0, stream>>>(gpart, out + 4 * kTokens);
}

// Round 12
// 83.952 us; speedup vs baseline: 1.4498x; 1.4498x over previous
//
#include <hip/hip_runtime.h>
#include <math.h>

namespace {
constexpr int kB = 4;
constexpr int kS = 4096;
constexpr int kH = 4096;
constexpr int kE = 16;
constexpr int kTokens = kB * kS;            // 16384
constexpr int kT = 4;                       // tokens per wave tile
constexpr int kEW = 8;                      // experts per wave tile (e-split 2)
constexpr int kThreads = 256;               // 4 waves: 2 token-groups x 2 e-halves
constexpr int kTokBlk = 8;                  // tokens per block
constexpr int kGrid = kTokens / kTokBlk;    // 2048 -> 8 blocks/CU, 32 waves/CU
constexpr int kChunk = 256;                 // floats of H per j-iter (float4/lane)
constexpr int kNC = kH / kChunk;            // 16
}  // namespace

// R5's winning pure-streaming structure (no LDS/barriers/waitcnt in the main
// loop, compiler-scheduled, max TLP) with the rule-#20 spill removed: no
// register array is EVER indexed by a runtime value (the acc[lane][e]
// publication is now a static lane==t ladder; top-2 avoids p[runtime]).
__global__ __launch_bounds__(kThreads) void router_main(
    const float* __restrict__ x, const float* __restrict__ W,
    float* __restrict__ out_probs,   // [kTokens][2]
    float* __restrict__ out_idx,     // [kTokens][2] (indices as float)
    float* __restrict__ gpart) {     // [kGrid][32]: cnt[16], psum[16] per block
  __shared__ float s_logit[kTokBlk][kE];
  __shared__ float s_cnt[kE];
  __shared__ float s_psum[kE];

  const int tid = threadIdx.x;
  const int wave = tid >> 6;
  const int lane = tid & 63;
  const int tg = wave >> 1;                 // token group: 0 or 1
  const int eo = (wave & 1) * kEW;          // expert offset: 0 or 8
  const int tokBase = blockIdx.x * kTokBlk;
  const int tok0 = tokBase + tg * kT;

  if (tid < kE) { s_cnt[tid] = 0.f; s_psum[tid] = 0.f; }

  const float* xb = x + (size_t)tok0 * kH + lane * 4;
  const float* wb = W + (size_t)eo * kH + lane * 4;

  float acc[kT][kEW];
#pragma unroll
  for (int t = 0; t < kT; ++t)
#pragma unroll
    for (int e = 0; e < kEW; ++e) acc[t][e] = 0.f;

  for (int j = 0; j < kNC; ++j) {
    const size_t off = (size_t)j * kChunk;
    float4 xv[kT];
#pragma unroll
    for (int t = 0; t < kT; ++t)
      xv[t] = *reinterpret_cast<const float4*>(xb + (size_t)t * kH + off);
    float4 wv[kEW];
#pragma unroll
    for (int e = 0; e < kEW; ++e)
      wv[e] = *reinterpret_cast<const float4*>(wb + (size_t)e * kH + off);
#pragma unroll
    for (int e = 0; e < kEW; ++e)
#pragma unroll
      for (int t = 0; t < kT; ++t) {
        acc[t][e] = fmaf(xv[t].x, wv[e].x, acc[t][e]);
        acc[t][e] = fmaf(xv[t].y, wv[e].y, acc[t][e]);
        acc[t][e] = fmaf(xv[t].z, wv[e].z, acc[t][e]);
        acc[t][e] = fmaf(xv[t].w, wv[e].w, acc[t][e]);
      }
  }

  // Butterfly: every lane ends with full-H sums for its 4x8 tile.
#pragma unroll
  for (int off = 1; off < 64; off <<= 1) {
#pragma unroll
    for (int t = 0; t < kT; ++t)
#pragma unroll
      for (int e = 0; e < kEW; ++e)
        acc[t][e] += __shfl_xor(acc[t][e], off, 64);
  }

  // Publish each token's 8-expert slice — STATIC acc indices only (rule #20).
#pragma unroll
  for (int t = 0; t < kT; ++t) {
    if (lane == t) {
      const int r = tg * kT + t;
#pragma unroll
      for (int e = 0; e < kEW; ++e) s_logit[r][eo + e] = acc[t][e];
    }
  }
  __syncthreads();

  // Wave 0, lanes 0..7: one token each — softmax, top-2, outputs, aux partials.
  if (wave == 0 && lane < kTokBlk) {
    const int tok = tokBase + lane;
    float l[kE];
#pragma unroll
    for (int e = 0; e < kE; ++e) l[e] = s_logit[lane][e];   // LDS: runtime ok

    float m = l[0];
#pragma unroll
    for (int e = 1; e < kE; ++e) m = fmaxf(m, l[e]);
    float p[kE];
    float s = 0.f;
#pragma unroll
    for (int e = 0; e < kE; ++e) { p[e] = __expf(l[e] - m); s += p[e]; }
    const float inv = 1.f / s;
#pragma unroll
    for (int e = 0; e < kE; ++e) p[e] *= inv;

    // top-2 on probs (reference: top_k AFTER softmax; ties -> lowest index).
    // All p[] accesses at compile-time indices (no p[i1]/p[i2] reads).
    int i1 = 0;
    float v1 = p[0];
#pragma unroll
    for (int e = 1; e < kE; ++e)
      if (p[e] > v1) { v1 = p[e]; i1 = e; }
    int i2 = -1;
    float v2 = -1.f;   // probs >= 0: first non-i1 max wins, lowest index on tie
#pragma unroll
    for (int e = 0; e < kE; ++e) {
      if (e == i1) continue;
      if (p[e] > v2) { v2 = p[e]; i2 = e; }
    }

    const float ns = 1.f / (v1 + v2);
    out_probs[tok * 2 + 0] = v1 * ns;
    out_probs[tok * 2 + 1] = v2 * ns;
    out_idx[tok * 2 + 0] = (float)i1;
    out_idx[tok * 2 + 1] = (float)i2;

#pragma unroll
    for (int e = 0; e < kE; ++e) atomicAdd(&s_psum[e], p[e]);
    atomicAdd(&s_cnt[i1], 1.f);
    atomicAdd(&s_cnt[i2], 1.f);
  }
  __syncthreads();
  // Per-block partials (coalesced store); reduced by aux_finish.
  if (tid < 2 * kE)
    gpart[(size_t)blockIdx.x * 2 * kE + tid] =
        (tid < kE) ? s_cnt[tid] : s_psum[tid - kE];
}

// Reduce per-block partials; aux = E * sum_e (cnt_e/B) * (psum_e/(B*S)).
__global__ __launch_bounds__(1024) void aux_finish(
    const float* __restrict__ gpart, float* __restrict__ out_aux) {
  __shared__ float s_red[32][32];
  __shared__ float s_final[32];
  const int tid = threadIdx.x;
  const int c = tid & 31;       // column: 0-15 cnt, 16-31 psum
  const int r0 = tid >> 5;      // row-slice 0..31
  float s = 0.f;
  for (int k = 0; k < kGrid / 32; ++k)
    s += gpart[(size_t)(r0 * (kGrid / 32) + k) * 32 + c];
  s_red[r0][c] = s;
  __syncthreads();
  if (tid < 32) {
    float t = 0.f;
    for (int r = 0; r < 32; ++r) t += s_red[r][tid];
    s_final[tid] = t;
  }
  __syncthreads();
  if (tid == 0) {
    double acc = 0.0;
    for (int e = 0; e < kE; ++e)
      acc += (double)s_final[e] * (double)s_final[kE + e];
    out_aux[0] = (float)(acc * (double)kE / ((double)kB * (double)kB * (double)kS));
  }
}

extern "C" void kernel_launch(void* const* d_in, const int* in_sizes, int n_in,
                              void* d_out, int out_size, void* d_ws, size_t ws_size,
                              hipStream_t stream) {
  const float* x = (const float*)d_in[0];   // [B,S,H] f32
  const float* W = (const float*)d_in[1];   // [E,H]   f32
  float* out = (float*)d_out;               // [32768 probs][32768 idx][1 aux]
  float* gpart = (float*)d_ws;              // [kGrid][32], fully overwritten

  router_main<<<kGrid, kThreads, 0, stream>>>(
      x, W, out, out + 2 * kTokens, gpart);
  aux_finish<<<1, 1024, 0, stream>>>(gpart, out + 4 * kTokens);
}

// Round 13
// 83.555 us; speedup vs baseline: 1.4567x; 1.0047x over previous
//
#include <hip/hip_runtime.h>
#include <math.h>

namespace {
constexpr int kB = 4;
constexpr int kS = 4096;
constexpr int kH = 4096;
constexpr int kE = 16;
constexpr int kTokens = kB * kS;            // 16384
constexpr int kT = 4;                       // tokens per wave tile
constexpr int kEW = 8;                      // experts per wave tile (e-split 2)
constexpr int kThreads = 256;               // 4 waves: 2 token-groups x 2 e-halves
constexpr int kTokBlk = 8;                  // tokens per block
constexpr int kGrid = kTokens / kTokBlk;    // 2048
constexpr int kChunk = 256;                 // floats of H per j-iter (float4/lane)
constexpr int kNC = kH / kChunk;            // 16
}  // namespace

// R12 (best: 84us) + depth-1 x prefetch. The x(j+1) loads are issued at the
// TOP of each j-body, before the W loads / FMA phases that consume x(j), so
// every wave keeps ~4KB outstanding through its whole compute phase
// (Little's law: R12 averaged only ~12KB in flight per CU -> 3.4 TB/s).
// No asm, no waitcnt, no LDS in the main loop — compiler schedules (the
// R8 lesson). Ping-pong via two NAMED arrays, zero runtime register
// indexing anywhere (rule #20, fixed in R12).
__global__ __launch_bounds__(kThreads) void router_main(
    const float* __restrict__ x, const float* __restrict__ W,
    float* __restrict__ out_probs,   // [kTokens][2]
    float* __restrict__ out_idx,     // [kTokens][2] (indices as float)
    float* __restrict__ gpart) {     // [kGrid][32]: cnt[16], psum[16] per block
  __shared__ float s_logit[kTokBlk][kE];
  __shared__ float s_cnt[kE];
  __shared__ float s_psum[kE];

  const int tid = threadIdx.x;
  const int wave = tid >> 6;
  const int lane = tid & 63;
  const int tg = wave >> 1;                 // token group: 0 or 1
  const int eo = (wave & 1) * kEW;          // expert offset: 0 or 8
  const int tokBase = blockIdx.x * kTokBlk;
  const int tok0 = tokBase + tg * kT;

  if (tid < kE) { s_cnt[tid] = 0.f; s_psum[tid] = 0.f; }

  const float* xb = x + (size_t)tok0 * kH + lane * 4;
  const float* wb = W + (size_t)eo * kH + lane * 4;

  float acc[kT][kEW];
#pragma unroll
  for (int t = 0; t < kT; ++t)
#pragma unroll
    for (int e = 0; e < kEW; ++e) acc[t][e] = 0.f;

  auto load_x = [&](int j, float4 (&xv)[kT]) {
    const size_t off = (size_t)j * kChunk;
#pragma unroll
    for (int t = 0; t < kT; ++t)
      xv[t] = *reinterpret_cast<const float4*>(xb + (size_t)t * kH + off);
  };

  // One j-step: prefetch x(j+1) into `nxt` FIRST, then W loads + FMAs on `cur`.
  auto step = [&](int j, const float4 (&cur)[kT], float4 (&nxt)[kT], bool pf) {
    if (pf) load_x(j + 1, nxt);
    const size_t off = (size_t)j * kChunk;
#pragma unroll
    for (int p = 0; p < 2; ++p) {
      float4 wv[4];
#pragma unroll
      for (int e = 0; e < 4; ++e)
        wv[e] = *reinterpret_cast<const float4*>(
            wb + (size_t)(p * 4 + e) * kH + off);
#pragma unroll
      for (int e = 0; e < 4; ++e) {
        const int ei = p * 4 + e;
#pragma unroll
        for (int t = 0; t < kT; ++t) {
          acc[t][ei] = fmaf(cur[t].x, wv[e].x, acc[t][ei]);
          acc[t][ei] = fmaf(cur[t].y, wv[e].y, acc[t][ei]);
          acc[t][ei] = fmaf(cur[t].z, wv[e].z, acc[t][ei]);
          acc[t][ei] = fmaf(cur[t].w, wv[e].w, acc[t][ei]);
        }
      }
    }
  };

  float4 xvA[kT], xvB[kT];
  load_x(0, xvA);

#pragma unroll 1
  for (int j = 0; j < kNC; j += 2) {
    step(j, xvA, xvB, true);                 // uses x(j),   prefetches x(j+1)
    step(j + 1, xvB, xvA, j + 2 < kNC);      // uses x(j+1), prefetches x(j+2)
  }

  // Butterfly: every lane ends with full-H sums for its 4x8 tile.
#pragma unroll
  for (int off = 1; off < 64; off <<= 1) {
#pragma unroll
    for (int t = 0; t < kT; ++t)
#pragma unroll
      for (int e = 0; e < kEW; ++e)
        acc[t][e] += __shfl_xor(acc[t][e], off, 64);
  }

  // Publish each token's 8-expert slice — STATIC acc indices only (rule #20).
#pragma unroll
  for (int t = 0; t < kT; ++t) {
    if (lane == t) {
      const int r = tg * kT + t;
#pragma unroll
      for (int e = 0; e < kEW; ++e) s_logit[r][eo + e] = acc[t][e];
    }
  }
  __syncthreads();

  // Wave 0, lanes 0..7: one token each — softmax, top-2, outputs, aux partials.
  if (wave == 0 && lane < kTokBlk) {
    const int tok = tokBase + lane;
    float l[kE];
#pragma unroll
    for (int e = 0; e < kE; ++e) l[e] = s_logit[lane][e];   // LDS: runtime ok

    float m = l[0];
#pragma unroll
    for (int e = 1; e < kE; ++e) m = fmaxf(m, l[e]);
    float p[kE];
    float s = 0.f;
#pragma unroll
    for (int e = 0; e < kE; ++e) { p[e] = __expf(l[e] - m); s += p[e]; }
    const float inv = 1.f / s;
#pragma unroll
    for (int e = 0; e < kE; ++e) p[e] *= inv;

    // top-2 on probs (reference: top_k AFTER softmax; ties -> lowest index).
    // All p[] accesses at compile-time indices (no p[i1]/p[i2] reads).
    int i1 = 0;
    float v1 = p[0];
#pragma unroll
    for (int e = 1; e < kE; ++e)
      if (p[e] > v1) { v1 = p[e]; i1 = e; }
    int i2 = -1;
    float v2 = -1.f;   // probs >= 0: first non-i1 max wins, lowest index on tie
#pragma unroll
    for (int e = 0; e < kE; ++e) {
      if (e == i1) continue;
      if (p[e] > v2) { v2 = p[e]; i2 = e; }
    }

    const float ns = 1.f / (v1 + v2);
    out_probs[tok * 2 + 0] = v1 * ns;
    out_probs[tok * 2 + 1] = v2 * ns;
    out_idx[tok * 2 + 0] = (float)i1;
    out_idx[tok * 2 + 1] = (float)i2;

#pragma unroll
    for (int e = 0; e < kE; ++e) atomicAdd(&s_psum[e], p[e]);
    atomicAdd(&s_cnt[i1], 1.f);
    atomicAdd(&s_cnt[i2], 1.f);
  }
  __syncthreads();
  // Per-block partials (coalesced store); reduced by aux_finish.
  if (tid < 2 * kE)
    gpart[(size_t)blockIdx.x * 2 * kE + tid] =
        (tid < kE) ? s_cnt[tid] : s_psum[tid - kE];
}

// Reduce per-block partials; aux = E * sum_e (cnt_e/B) * (psum_e/(B*S)).
__global__ __launch_bounds__(1024) void aux_finish(
    const float* __restrict__ gpart, float* __restrict__ out_aux) {
  __shared__ float s_red[32][32];
  __shared__ float s_final[32];
  const int tid = threadIdx.x;
  const int c = tid & 31;       // column: 0-15 cnt, 16-31 psum
  const int r0 = tid >> 5;      // row-slice 0..31
  float s = 0.f;
  for (int k = 0; k < kGrid / 32; ++k)
    s += gpart[(size_t)(r0 * (kGrid / 32) + k) * 32 + c];
  s_red[r0][c] = s;
  __syncthreads();
  if (tid < 32) {
    float t = 0.f;
    for (int r = 0; r < 32; ++r) t += s_red[r][tid];
    s_final[tid] = t;
  }
  __syncthreads();
  if (tid == 0) {
    double acc = 0.0;
    for (int e = 0; e < kE; ++e)
      acc += (double)s_final[e] * (double)s_final[kE + e];
    out_aux[0] = (float)(acc * (double)kE / ((double)kB * (double)kB * (double)kS));
  }
}

extern "C" void kernel_launch(void* const* d_in, const int* in_sizes, int n_in,
                              void* d_out, int out_size, void* d_ws, size_t ws_size,
                              hipStream_t stream) {
  const float* x = (const float*)d_in[0];   // [B,S,H] f32
  const float* W = (const float*)d_in[1];   // [E,H]   f32
  float* out = (float*)d_out;               // [32768 probs][32768 idx][1 aux]
  float* gpart = (float*)d_ws;              // [kGrid][32], fully overwritten

  router_main<<<kGrid, kThreads, 0, stream>>>(
      x, W, out, out + 2 * kTokens, gpart);
  aux_finish<<<1, 1024, 0, stream>>>(gpart, out + 4 * kTokens);
}